// Round 5
// baseline (286.906 us; speedup 1.0000x reference)
//
#include <hip/hip_runtime.h>
#include <math.h>

typedef _Float16 f16;
typedef _Float16 f16x8 __attribute__((ext_vector_type(8)));
typedef float f32x4 __attribute__((ext_vector_type(4)));

#define HEAD 128
#define EDIM 1536
#define NI   3200
#define NIP  3328   // NI padded to 13*256
#define HDIM 768
#define BATCH 4
#define SEQ  2048
#define MTOT (BATCH*SEQ)

__device__ __forceinline__ void gld_lds16(const void* g, void* l) {
  __builtin_amdgcn_global_load_lds(
      (const __attribute__((address_space(1))) void*)g,
      (__attribute__((address_space(3))) void*)l, 16, 0, 0);
}

// ---------------- prep kernels ----------------
__global__ __launch_bounds__(256) void cast_f32_f16_k(const float* __restrict__ in,
                                                      f16* __restrict__ out, int n4) {
  int i = blockIdx.x * 256 + threadIdx.x;
  if (i >= n4) return;
  float4 x = ((const float4*)in)[i];
  union { f16 h[4]; short4 s; } u;
  u.h[0] = (f16)x.x; u.h[1] = (f16)x.y; u.h[2] = (f16)x.z; u.h[3] = (f16)x.w;
  ((short4*)out)[i] = u.s;
}

// out[C][R] = in[R][C], f32 -> f16. grid = (C/32, R/32)
__global__ __launch_bounds__(256) void transpose_cast_k(const float* __restrict__ in, int ld_in,
                                                        f16* __restrict__ out, int ld_out) {
  __shared__ float tile[32][33];
  int c = threadIdx.x & 31, r0 = threadIdx.x >> 5;
  int ib = blockIdx.y * 32, jb = blockIdx.x * 32;
#pragma unroll
  for (int rr = 0; rr < 32; rr += 8)
    tile[r0 + rr][c] = in[(size_t)(ib + r0 + rr) * ld_in + jb + c];
  __syncthreads();
#pragma unroll
  for (int rr = 0; rr < 32; rr += 8)
    out[(size_t)(jb + r0 + rr) * ld_out + ib + c] = (f16)tile[c][r0 + rr];
}

// out[C][R] = in[R][C], f16 -> f16, batched over z. grid = (C/32, R/32, nb)
__global__ __launch_bounds__(256) void transpose_f16_k(const f16* __restrict__ in, int ld_in,
                                                       long long sIn,
                                                       f16* __restrict__ out, int ld_out,
                                                       long long sOut) {
  __shared__ f16 tile[32][33];
  in  += (size_t)blockIdx.z * sIn;
  out += (size_t)blockIdx.z * sOut;
  int c = threadIdx.x & 31, r0 = threadIdx.x >> 5;
  int ib = blockIdx.y * 32, jb = blockIdx.x * 32;
#pragma unroll
  for (int rr = 0; rr < 32; rr += 8)
    tile[r0 + rr][c] = in[(size_t)(ib + r0 + rr) * ld_in + jb + c];
  __syncthreads();
#pragma unroll
  for (int rr = 0; rr < 32; rr += 8)
    out[(size_t)(jb + r0 + rr) * ld_out + ib + c] = tile[c][r0 + rr];
}

__global__ __launch_bounds__(256) void rope_tables_k(float* __restrict__ cosT,
                                                     float* __restrict__ sinT) {
  int id = blockIdx.x * 256 + threadIdx.x;   // < 2048*64
  int pos = id >> 6, i = id & 63;
  float ang = (float)pos / powf(10000.0f, (float)(2 * i) / 128.0f);
  float cv = cosf(ang), sv = sinf(ang);
  cosT[pos * HEAD + 2 * i]     = cv;
  cosT[pos * HEAD + 2 * i + 1] = cv;
  sinT[pos * HEAD + 2 * i]     = sv;
  sinT[pos * HEAD + 2 * i + 1] = sv;
}

__global__ __launch_bounds__(256) void addmask_k(const float* __restrict__ mask,
                                                 float* __restrict__ am) {
  int i = blockIdx.x * 256 + threadIdx.x;    // BATCH*SEQ
  am[i] = (1.0f - mask[i]) * -1e12f;
}

// ---------------- 256x256 8-wave pipelined GEMM: C = A[M][K] * Bt[N][K]^T ----------------
// BK=32, 4 LDS buffers (128KiB), depth-3 prefetch, 1 barrier/step, counted vmcnt(8),
// setprio around MFMA cluster. [256][32] f16 LDS rows hit the 8-cycle b128 bank floor.
// MODE 0: GEMM1 -> silu, u/v to Xh; qk cols -> gamma/beta + RoPE -> Qh,Kh (N padded to NIP)
// MODE 1: scores -> *1/sqrt(128) + addmask, f32 out  (batches flattened in grid.y)
// MODE 2: attn@v -> * u gate, f16 out                (batches flattened in grid.y)
template <int MODE>
__global__ __launch_bounds__(512, 2)
void gemm256(const f16* __restrict__ A, int lda,
             const f16* __restrict__ B0, int ldb, long long sB, int bshift,
             int K,
             float* __restrict__ outF,
             f16* __restrict__ outH, f16* __restrict__ outH2, f16* __restrict__ outH3,
             const float* __restrict__ c0,
             const float* __restrict__ c1, const float* __restrict__ c2,
             const float* __restrict__ c3, const float* __restrict__ c4,
             const f16* __restrict__ hA) {
  __shared__ f16 LS[4][2][256 * 32];   // [buf][A|B][row*32+k], linear for global_load_lds
  // T1: XCD swizzle on flattened (x,y); grid.x*grid.y % 8 == 0 for all launches
  int bx, by;
  {
    int gx = gridDim.x;
    int id = blockIdx.y * gx + blockIdx.x;
    int cpx = (gx * gridDim.y) >> 3;
    int sw = (id & 7) * cpx + (id >> 3);
    bx = sw % gx; by = sw / gx;
  }
  const int m0 = by * 256, n0 = bx * 256;
  const int t = threadIdx.x;
  const int lane = t & 63, w = t >> 6;
  const int wr = w >> 2, wc = w & 3;        // 2M x 4N wave grid; per-wave 128x64 out
  const int lr = lane & 15, kg = lane >> 4;
  const int bb = by >> bshift;              // batch select (flattened grids)
  const f16* Bb = B0 + (size_t)bb * sB;

  // staging: thread t covers rows (t>>2) and (t>>2)+128, 16B k-slot (t&3)
  const f16* gA = A  + (size_t)(m0 + (t >> 2)) * lda + (t & 3) * 8;
  const f16* gB = Bb + (size_t)(n0 + (t >> 2)) * ldb + (t & 3) * 8;

  f32x4 acc[8][4];
#pragma unroll
  for (int i = 0; i < 8; ++i)
#pragma unroll
    for (int j = 0; j < 4; ++j) acc[i][j] = f32x4{0.f, 0.f, 0.f, 0.f};

  auto stage = [&](int kt) {   // 4 loads/thread; LDS dest wave-uniform, src per-lane
    char* SA = (char*)(&LS[kt & 3][0][0]) + w * 1024;
    char* SB = (char*)(&LS[kt & 3][1][0]) + w * 1024;
    const f16* a = gA + kt * 32;
    const f16* b = gB + kt * 32;
    gld_lds16(a,                       SA);
    gld_lds16(a + (size_t)128 * lda,   SA + 8192);
    gld_lds16(b,                       SB);
    gld_lds16(b + (size_t)128 * ldb,   SB + 8192);
  };

  const int ns = K >> 5;
  stage(0); stage(1); stage(2);              // 12 loads in flight
  for (int s = 0; s < ns; ++s) {
    // retire stage(s) (oldest 4); keep later stages in flight
    if (s + 2 < ns)      asm volatile("s_waitcnt vmcnt(8)" ::: "memory");
    else if (s + 1 < ns) asm volatile("s_waitcnt vmcnt(4)" ::: "memory");
    else                 asm volatile("s_waitcnt vmcnt(0)" ::: "memory");
    __builtin_amdgcn_s_barrier();            // publish stage(s) to all waves
    asm volatile("" ::: "memory");           // pin loads/stages below the barrier
    if (s + 3 < ns) stage(s + 3);            // target buf freed 2 barriers ago
    const f16* SA = &LS[s & 3][0][0];
    const f16* SB = &LS[s & 3][1][0];
    f16x8 af[8], bf[4];
#pragma unroll
    for (int i = 0; i < 8; ++i)
      af[i] = *(const f16x8*)&SA[(wr * 128 + i * 16 + lr) * 32 + kg * 8];
#pragma unroll
    for (int j = 0; j < 4; ++j)
      bf[j] = *(const f16x8*)&SB[(wc * 64 + j * 16 + lr) * 32 + kg * 8];
    __builtin_amdgcn_s_setprio(1);
#pragma unroll
    for (int i = 0; i < 8; ++i)
#pragma unroll
      for (int j = 0; j < 4; ++j)
        acc[i][j] = __builtin_amdgcn_mfma_f32_16x16x32_f16(af[i], bf[j], acc[i][j], 0, 0, 0);
    __builtin_amdgcn_s_setprio(0);
  }

  // epilogue: C elem (row,col): col = lane&15, row = (lane>>4)*4 + r  [measured layout]
  const int colbase = n0 + wc * 64;          // wave-uniform 64-col stripe
  if (MODE == 0 && colbase >= NI) return;    // padded cols: skip
#pragma unroll
  for (int i = 0; i < 8; ++i) {
#pragma unroll
    for (int j = 0; j < 4; ++j) {
#pragma unroll
      for (int r = 0; r < 4; ++r) {
        int row = m0 + wr * 128 + i * 16 + kg * 4 + r;
        int col = colbase + j * 16 + lr;
        float x = acc[i][j][r];
        if (MODE == 0) {
          float xb = x + c0[col];
          float sv_ = xb * __builtin_amdgcn_rcpf(1.0f + __expf(-xb));   // silu
          if (colbase >= 3072) {             // qk stripes (colbase 3072 / 3136)
            int c = col - 3072;
            float pv = __shfl_xor(sv_, 1, 64);   // partner col c^1 lives in lane^1
            int pos = row & (SEQ - 1);
            float cv = c3[pos * HEAD + c], sn = c4[pos * HEAD + c];
            float q  = sv_ * c1[c] + c2[c];
            float pq = pv  * c1[c ^ 1] + c2[c ^ 1];
            float x2q = (c & 1) ? pq : -pq;
            outH2[row * HEAD + c] = (f16)(q * cv + x2q * sn);
            float kk = sv_ * c1[128 + c] + c2[128 + c];
            float pk = pv  * c1[128 + (c ^ 1)] + c2[128 + (c ^ 1)];
            float x2k = (c & 1) ? pk : -pk;
            outH3[row * HEAD + c] = (f16)(kk * cv + x2k * sn);
          } else {
            outH[(size_t)row * 3072 + col] = (f16)sv_;   // u | v
          }
        } else if (MODE == 1) {
          outF[(size_t)row * SEQ + col] = x * 0.08838834764831845f + c0[bb * SEQ + col];
        } else if (MODE == 2) {
          float uu = (float)hA[(size_t)row * 3072 + col];   // u gate
          outH[(size_t)row * EDIM + col] = (f16)(x * uu);
        }
      }
    }
  }
}

// ---------------- final GEMM (N=768): R3-style 128x128 2-phase dbuf ----------------
__global__ __launch_bounds__(256, 4)
void gemm_final(const f16* __restrict__ A, int lda,
                const f16* __restrict__ Bt, int ldb, int K,
                float* __restrict__ outF, const float* __restrict__ c0) {
  __shared__ f16 As0[128 * 32];
  __shared__ f16 As1[128 * 32];
  __shared__ f16 Bs0[128 * 32];
  __shared__ f16 Bs1[128 * 32];
  const int m0 = blockIdx.y * 128, n0 = blockIdx.x * 128;
  const int t = threadIdx.x;
  const int lane = t & 63, w = t >> 6;
  const int wr = w >> 1, wc = w & 1;
  const int lr = lane & 15, kg = lane >> 4;

  const f16* ga = A  + (size_t)(m0 + (t >> 2)) * lda + (t & 3) * 8;
  const f16* gb = Bt + (size_t)(n0 + (t >> 2)) * ldb + (t & 3) * 8;

  f32x4 acc[4][4];
#pragma unroll
  for (int i = 0; i < 4; ++i)
#pragma unroll
    for (int j = 0; j < 4; ++j) acc[i][j] = f32x4{0.f, 0.f, 0.f, 0.f};

  auto stage = [&](f16* AS, f16* BS, int kk) {
    gld_lds16(ga + kk,                    (char*)AS + w * 1024);
    gld_lds16(ga + (size_t)64 * lda + kk, (char*)AS + w * 1024 + 4096);
    gld_lds16(gb + kk,                    (char*)BS + w * 1024);
    gld_lds16(gb + (size_t)64 * ldb + kk, (char*)BS + w * 1024 + 4096);
  };
  auto compute = [&](const f16* AS, const f16* BS) {
    f16x8 af[4], bf[4];
#pragma unroll
    for (int i = 0; i < 4; ++i) {
      af[i] = *(const f16x8*)&AS[(wr * 64 + i * 16 + lr) * 32 + kg * 8];
      bf[i] = *(const f16x8*)&BS[(wc * 64 + i * 16 + lr) * 32 + kg * 8];
    }
#pragma unroll
    for (int i = 0; i < 4; ++i)
#pragma unroll
      for (int j = 0; j < 4; ++j)
        acc[i][j] = __builtin_amdgcn_mfma_f32_16x16x32_f16(af[i], bf[j], acc[i][j], 0, 0, 0);
  };

  stage(As0, Bs0, 0);
  __syncthreads();
  for (int k0 = 0; k0 < K; k0 += 64) {
    if (k0 + 32 < K) stage(As1, Bs1, k0 + 32);
    compute(As0, Bs0);
    __syncthreads();
    if (k0 + 64 < K) stage(As0, Bs0, k0 + 64);
    compute(As1, Bs1);
    __syncthreads();
  }

#pragma unroll
  for (int i = 0; i < 4; ++i)
#pragma unroll
    for (int j = 0; j < 4; ++j)
#pragma unroll
      for (int r = 0; r < 4; ++r) {
        int row = m0 + wr * 64 + i * 16 + kg * 4 + r;
        int col = n0 + wc * 64 + j * 16 + lr;
        outF[(size_t)row * HDIM + col] = acc[i][j][r] + c0[col];
      }
}

// ---------------- softmax_plus: one block per row, in-place f32 -> f16 ----------------
__global__ __launch_bounds__(256) void softmax_plus_k(float* __restrict__ S) {
  __shared__ float red[4];
  const int t = threadIdx.x;
  float* sr = S + (size_t)blockIdx.x * SEQ;
  float v[8];
  *(float4*)&v[0] = ((const float4*)sr)[t * 2];
  *(float4*)&v[4] = ((const float4*)sr)[t * 2 + 1];

  float cnt = 0.f;
#pragma unroll
  for (int i = 0; i < 8; ++i) cnt += (v[i] > -1e11f) ? 1.0f : 0.0f;
#pragma unroll
  for (int o = 32; o; o >>= 1) cnt += __shfl_xor(cnt, o, 64);
  if ((t & 63) == 0) red[t >> 6] = cnt;
  __syncthreads();
  cnt = red[0] + red[1] + red[2] + red[3];
  float scale = __logf(fmaxf(cnt, 1.0f)) * 0.16025848f;   // 1/ln(512)

  float mx = -INFINITY;
#pragma unroll
  for (int i = 0; i < 8; ++i) { v[i] *= scale; mx = fmaxf(mx, v[i]); }
#pragma unroll
  for (int o = 32; o; o >>= 1) mx = fmaxf(mx, __shfl_xor(mx, o, 64));
  __syncthreads();
  if ((t & 63) == 0) red[t >> 6] = mx;
  __syncthreads();
  mx = fmaxf(fmaxf(red[0], red[1]), fmaxf(red[2], red[3]));

  float p[8], sum = 0.f;
#pragma unroll
  for (int i = 0; i < 8; ++i) { p[i] = __expf(v[i] - mx); sum += p[i]; }
#pragma unroll
  for (int o = 32; o; o >>= 1) sum += __shfl_xor(sum, o, 64);
  __syncthreads();
  if ((t & 63) == 0) red[t >> 6] = sum;
  __syncthreads();
  sum = red[0] + red[1] + red[2] + red[3];
  float inv = __builtin_amdgcn_rcpf(sum);

  union { f16 h[8]; uint4 u4; } pk;
#pragma unroll
  for (int i = 0; i < 8; ++i) pk.h[i] = (f16)(p[i] * inv);
  ((uint4*)sr)[t] = pk.u4;   // all reads completed before last barrier
}

// ---------------- launch ----------------
extern "C" void kernel_launch(void* const* d_in, const int* in_sizes, int n_in,
                              void* d_out, int out_size, void* d_ws, size_t ws_size,
                              hipStream_t stream) {
  const float* hs    = (const float*)d_in[0];
  const float* mask  = (const float*)d_in[1];
  const float* Wi    = (const float*)d_in[2];
  const float* bi    = (const float*)d_in[3];
  const float* gamma = (const float*)d_in[4];
  const float* beta  = (const float*)d_in[5];
  const float* Wo    = (const float*)d_in[6];
  const float* bo    = (const float*)d_in[7];
  float* out = (float*)d_out;

  // batched path needs ~195 MB; fall back to per-batch serial if ws is smaller
  const int nb = (ws_size >= ((size_t)200 << 20)) ? BATCH : 1;

  char* p = (char*)d_ws;
  auto alloc = [&](size_t b) { char* r = p; p += (b + 255) & ~(size_t)255; return r; };
  f16*   Xh   = (f16*)  alloc((size_t)MTOT * 3072 * 2);  // u|v
  f16*   Qh   = (f16*)  alloc((size_t)MTOT * HEAD * 2);
  f16*   Kh   = (f16*)  alloc((size_t)MTOT * HEAD * 2);
  f16*   Ah   = (f16*)  alloc((size_t)MTOT * HDIM * 2);
  f16*   WiT  = (f16*)  alloc((size_t)NIP * HDIM * 2);   // rows 3200..3327 pad (unread cols)
  f16*   WoT  = (f16*)  alloc((size_t)HDIM * EDIM * 2);
  float* cosT = (float*)alloc((size_t)SEQ * HEAD * 4);
  float* sinT = (float*)alloc((size_t)SEQ * HEAD * 4);
  float* am   = (float*)alloc((size_t)BATCH * SEQ * 4);
  f16*   G    = (f16*)  alloc((size_t)MTOT * EDIM * 2);
  float* Sws  = (float*)alloc((size_t)nb * SEQ * SEQ * 4);
  f16*   Vt   = (f16*)  alloc((size_t)nb * EDIM * SEQ * 2);

  cast_f32_f16_k<<<dim3(MTOT * HDIM / 4 / 256), 256, 0, stream>>>(hs, Ah, MTOT * HDIM / 4);
  transpose_cast_k<<<dim3(NI / 32, HDIM / 32), 256, 0, stream>>>(Wi, NI, WiT, HDIM);
  transpose_cast_k<<<dim3(HDIM / 32, EDIM / 32), 256, 0, stream>>>(Wo, HDIM, WoT, EDIM);
  rope_tables_k<<<dim3(SEQ * 64 / 256), 256, 0, stream>>>(cosT, sinT);
  addmask_k<<<dim3(BATCH * SEQ / 256), 256, 0, stream>>>(mask, am);

  gemm256<0><<<dim3(NIP / 256, MTOT / 256), 512, 0, stream>>>(
      Ah, HDIM, WiT, HDIM, 0, 30, HDIM,
      nullptr, Xh, Qh, Kh, bi, gamma, beta, cosT, sinT, nullptr);

  const int bsh = (nb == BATCH) ? 3 : 30;   // by>>3 selects batch when flattened
  for (int b0 = 0; b0 < BATCH; b0 += nb) {
    transpose_f16_k<<<dim3(EDIM / 32, SEQ / 32, nb), 256, 0, stream>>>(
        Xh + (size_t)b0 * SEQ * 3072 + 1536, 3072, (long long)SEQ * 3072,
        Vt, SEQ, (long long)EDIM * SEQ);
    gemm256<1><<<dim3(SEQ / 256, nb * SEQ / 256), 512, 0, stream>>>(
        Qh + (size_t)b0 * SEQ * HEAD, HEAD,
        Kh + (size_t)b0 * SEQ * HEAD, HEAD, (long long)SEQ * HEAD, bsh, HEAD,
        Sws, nullptr, nullptr, nullptr,
        am + b0 * SEQ, nullptr, nullptr, nullptr, nullptr, nullptr);
    softmax_plus_k<<<dim3(nb * SEQ), 256, 0, stream>>>(Sws);
    gemm256<2><<<dim3(EDIM / 256, nb * SEQ / 256), 512, 0, stream>>>(
        (const f16*)Sws, 4096,
        Vt, SEQ, (long long)EDIM * SEQ, bsh, SEQ,
        nullptr, G + (size_t)b0 * SEQ * EDIM, nullptr, nullptr,
        nullptr, nullptr, nullptr, nullptr, nullptr,
        Xh + (size_t)b0 * SEQ * 3072);
  }

  gemm_final<<<dim3(HDIM / 128, MTOT / 128), 256, 0, stream>>>(
      G, EDIM, WoT, EDIM, EDIM, out, bo);
}

// Round 6
// 272.815 us; speedup vs baseline: 1.0517x; 1.0517x over previous
//
#include <hip/hip_runtime.h>
#include <math.h>

typedef _Float16 f16;
typedef _Float16 f16x8 __attribute__((ext_vector_type(8)));
typedef float f32x4 __attribute__((ext_vector_type(4)));

#define HEAD 128
#define EDIM 1536
#define NI   3200
#define NIP  3328   // NI padded to 13*256
#define HDIM 768
#define BATCH 4
#define SEQ  2048
#define MTOT (BATCH*SEQ)

__device__ __forceinline__ void gld_lds16(const void* g, void* l) {
  __builtin_amdgcn_global_load_lds(
      (const __attribute__((address_space(1))) void*)g,
      (__attribute__((address_space(3))) void*)l, 16, 0, 0);
}

// ---------------- prep kernels ----------------
__global__ __launch_bounds__(256) void cast_f32_f16_k(const float* __restrict__ in,
                                                      f16* __restrict__ out, int n4) {
  int i = blockIdx.x * 256 + threadIdx.x;
  if (i >= n4) return;
  float4 x = ((const float4*)in)[i];
  union { f16 h[4]; short4 s; } u;
  u.h[0] = (f16)x.x; u.h[1] = (f16)x.y; u.h[2] = (f16)x.z; u.h[3] = (f16)x.w;
  ((short4*)out)[i] = u.s;
}

__global__ __launch_bounds__(256) void transpose_cast_k(const float* __restrict__ in, int ld_in,
                                                        f16* __restrict__ out, int ld_out) {
  __shared__ float tile[32][33];
  int c = threadIdx.x & 31, r0 = threadIdx.x >> 5;
  int ib = blockIdx.y * 32, jb = blockIdx.x * 32;
#pragma unroll
  for (int rr = 0; rr < 32; rr += 8)
    tile[r0 + rr][c] = in[(size_t)(ib + r0 + rr) * ld_in + jb + c];
  __syncthreads();
#pragma unroll
  for (int rr = 0; rr < 32; rr += 8)
    out[(size_t)(jb + r0 + rr) * ld_out + ib + c] = (f16)tile[c][r0 + rr];
}

__global__ __launch_bounds__(256) void transpose_f16_k(const f16* __restrict__ in, int ld_in,
                                                       long long sIn,
                                                       f16* __restrict__ out, int ld_out,
                                                       long long sOut) {
  __shared__ f16 tile[32][33];
  in  += (size_t)blockIdx.z * sIn;
  out += (size_t)blockIdx.z * sOut;
  int c = threadIdx.x & 31, r0 = threadIdx.x >> 5;
  int ib = blockIdx.y * 32, jb = blockIdx.x * 32;
#pragma unroll
  for (int rr = 0; rr < 32; rr += 8)
    tile[r0 + rr][c] = in[(size_t)(ib + r0 + rr) * ld_in + jb + c];
  __syncthreads();
#pragma unroll
  for (int rr = 0; rr < 32; rr += 8)
    out[(size_t)(jb + r0 + rr) * ld_out + ib + c] = tile[c][r0 + rr];
}

__global__ __launch_bounds__(256) void rope_tables_k(float* __restrict__ cosT,
                                                     float* __restrict__ sinT) {
  int id = blockIdx.x * 256 + threadIdx.x;   // < 2048*64
  int pos = id >> 6, i = id & 63;
  float ang = (float)pos / powf(10000.0f, (float)(2 * i) / 128.0f);
  float cv = cosf(ang), sv = sinf(ang);
  cosT[pos * HEAD + 2 * i]     = cv;
  cosT[pos * HEAD + 2 * i + 1] = cv;
  sinT[pos * HEAD + 2 * i]     = sv;
  sinT[pos * HEAD + 2 * i + 1] = sv;
}

__global__ __launch_bounds__(256) void addmask_k(const float* __restrict__ mask,
                                                 float* __restrict__ am) {
  int i = blockIdx.x * 256 + threadIdx.x;    // BATCH*SEQ
  am[i] = (1.0f - mask[i]) * -1e12f;
}

// ============ 256x256 8-wave, 8-phase pipelined GEMM (m201 structure) ============
// BK=64 per K-tile, 2 LDS buffers (128 KiB), 4 phases/tile, counted vmcnt(4) once
// per tile (never 0 mid-loop), setprio around each 16-MFMA quadrant cluster.
// T2 swizzle: slot ^= (row&7) applied on global SOURCE addr (LDS linear for
// global_load_lds) and identically on the ds_read side.
// Ledger (steady state, per tile t): ph0 stages A0(t+1), ph1 A1(t+1),
// ph2 B0(t+2), ph3 B1(t+2); at t.ph3 vmcnt(4) retires all of tile t+1,
// leaves B(t+2) in flight. Half-region free-before-restage verified per wave-role.
// MODE 0: GEMM1 -> silu, u/v to Xh; qk cols -> gamma/beta + RoPE -> Qh,Kh
// MODE 2: attn@v -> * u gate, f16 out (batches flattened in grid.y)
template <int MODE>
__global__ __launch_bounds__(512, 2)
void gemm8p(const f16* __restrict__ A, int lda,
            const f16* __restrict__ B0, int ldb, long long sB, int bshift, int K,
            f16* __restrict__ outH, f16* __restrict__ outH2, f16* __restrict__ outH3,
            const float* __restrict__ c0, const float* __restrict__ c1,
            const float* __restrict__ c2, const float* __restrict__ c3,
            const float* __restrict__ c4, const f16* __restrict__ hA) {
  __shared__ f16 LS[2][2][2][2][4096];  // [buf][mat][half][p][512*8] = 128 KiB
  int bx, by;
  {
    int gx = gridDim.x;
    int id = blockIdx.y * gx + blockIdx.x;
    int cpx = (gx * gridDim.y) >> 3;
    int sw = (id & 7) * cpx + (id >> 3);
    bx = sw % gx; by = sw / gx;
  }
  const int m0 = by * 256, n0 = bx * 256;
  const int t = threadIdx.x;
  const int lane = t & 63, w = t >> 6;
  const int wr = w >> 2, wc = w & 3;      // 2M x 4N waves; per-wave C = 128x64
  const int lr = lane & 15, kg = lane >> 4;
  const int bb = by >> bshift;
  const f16* Bb = B0 + (size_t)bb * sB;

  // staging map: thread -> row rb (64 rows/round), swizzled 16B slot
  const int rb = t >> 3;
  const int sl = ((t & 7) ^ (rb & 7)) << 3;          // f16 offset of slot
  const f16* gA = A  + (size_t)(m0 + rb) * lda + sl;
  const f16* gB = Bb + (size_t)(n0 + rb) * ldb + sl;
  char* lA = (char*)LS + w * 1024;
  char* lB = (char*)LS + 32768 + w * 1024;

  auto stageA = [&](int kt, int h) {                 // one half-tile = 2 loads
    const f16* s = gA + (size_t)(h << 7) * lda + (kt << 6);
    char* d = lA + ((kt & 1) << 16) + (h << 14);
    gld_lds16(s, d);
    gld_lds16(s + ((size_t)lda << 6), d + 8192);
  };
  auto stageB = [&](int kt, int h) {
    const f16* s = gB + (size_t)(h << 7) * ldb + (kt << 6);
    char* d = lB + ((kt & 1) << 16) + (h << 14);
    gld_lds16(s, d);
    gld_lds16(s + ((size_t)ldb << 6), d + 8192);
  };

  // read side: row pitch 128B; slot = (ks*4+kg) ^ (row&7), row&7 == lr&7
  const char* RA = (const char*)LS + ((wr * 128 + lr) << 7);
  const char* RB = (const char*)LS + 32768 + ((wc * 64 + lr) << 7);
  const int sw0 = (kg ^ (lr & 7)) << 4;
  const int sw1 = ((4 + kg) ^ (lr & 7)) << 4;

  f32x4 acc[8][4];
#pragma unroll
  for (int i = 0; i < 8; ++i)
#pragma unroll
    for (int j = 0; j < 4; ++j) acc[i][j] = f32x4{0.f, 0.f, 0.f, 0.f};

  const int nt = K >> 6;
  // prologue: tile0 fully + tile1 B-halves; retire tile0, keep B(1) in flight
  stageA(0, 0); stageA(0, 1); stageB(0, 0); stageB(0, 1);
  asm volatile("" ::: "memory");
  if (nt > 1) {
    stageB(1, 0); stageB(1, 1);
    asm volatile("s_waitcnt vmcnt(4)" ::: "memory");
  } else {
    asm volatile("s_waitcnt vmcnt(0)" ::: "memory");
  }
  __builtin_amdgcn_s_barrier();
  asm volatile("" ::: "memory");

  for (int tt = 0; tt < nt; ++tt) {
    const char* SA = RA + ((tt & 1) << 16);
    const char* SB = RB + ((tt & 1) << 16);
    f16x8 a0[4][2], a1[4][2], b0[2][2], b1[2][2];
    // ---------- phase 0: read a0,b0; stage A0(t+1); MFMA q0 = acc[0..3][0..1]
#pragma unroll
    for (int i2 = 0; i2 < 4; ++i2) {
      a0[i2][0] = *(const f16x8*)(SA + (i2 << 11) + sw0);
      a0[i2][1] = *(const f16x8*)(SA + (i2 << 11) + sw1);
    }
#pragma unroll
    for (int j2 = 0; j2 < 2; ++j2) {
      b0[j2][0] = *(const f16x8*)(SB + (j2 << 11) + sw0);
      b0[j2][1] = *(const f16x8*)(SB + (j2 << 11) + sw1);
    }
    if (tt + 1 < nt) stageA(tt + 1, 0);
    __builtin_amdgcn_s_barrier();
    asm volatile("" ::: "memory");
    __builtin_amdgcn_s_setprio(1);
#pragma unroll
    for (int ks = 0; ks < 2; ++ks)
#pragma unroll
      for (int i2 = 0; i2 < 4; ++i2)
#pragma unroll
        for (int j2 = 0; j2 < 2; ++j2)
          acc[i2][j2] = __builtin_amdgcn_mfma_f32_16x16x32_f16(
              a0[i2][ks], b0[j2][ks], acc[i2][j2], 0, 0, 0);
    __builtin_amdgcn_s_setprio(0);
    __builtin_amdgcn_s_barrier();
    asm volatile("" ::: "memory");
    // ---------- phase 1: read b1; stage A1(t+1); MFMA q1 = acc[0..3][2..3]
#pragma unroll
    for (int j2 = 0; j2 < 2; ++j2) {
      b1[j2][0] = *(const f16x8*)(SB + ((2 + j2) << 11) + sw0);
      b1[j2][1] = *(const f16x8*)(SB + ((2 + j2) << 11) + sw1);
    }
    if (tt + 1 < nt) stageA(tt + 1, 1);
    __builtin_amdgcn_s_barrier();
    asm volatile("" ::: "memory");
    __builtin_amdgcn_s_setprio(1);
#pragma unroll
    for (int ks = 0; ks < 2; ++ks)
#pragma unroll
      for (int i2 = 0; i2 < 4; ++i2)
#pragma unroll
        for (int j2 = 0; j2 < 2; ++j2)
          acc[i2][2 + j2] = __builtin_amdgcn_mfma_f32_16x16x32_f16(
              a0[i2][ks], b1[j2][ks], acc[i2][2 + j2], 0, 0, 0);
    __builtin_amdgcn_s_setprio(0);
    __builtin_amdgcn_s_barrier();
    asm volatile("" ::: "memory");
    // ---------- phase 2: read a1; stage B0(t+2); MFMA q2 = acc[4..7][0..1]
#pragma unroll
    for (int i2 = 0; i2 < 4; ++i2) {
      a1[i2][0] = *(const f16x8*)(SA + ((4 + i2) << 11) + sw0);
      a1[i2][1] = *(const f16x8*)(SA + ((4 + i2) << 11) + sw1);
    }
    if (tt + 2 < nt) stageB(tt + 2, 0);
    __builtin_amdgcn_s_barrier();
    asm volatile("" ::: "memory");
    __builtin_amdgcn_s_setprio(1);
#pragma unroll
    for (int ks = 0; ks < 2; ++ks)
#pragma unroll
      for (int i2 = 0; i2 < 4; ++i2)
#pragma unroll
        for (int j2 = 0; j2 < 2; ++j2)
          acc[4 + i2][j2] = __builtin_amdgcn_mfma_f32_16x16x32_f16(
              a1[i2][ks], b0[j2][ks], acc[4 + i2][j2], 0, 0, 0);
    __builtin_amdgcn_s_setprio(0);
    __builtin_amdgcn_s_barrier();
    asm volatile("" ::: "memory");
    // ---------- phase 3: stage B1(t+2); MFMA q3 = acc[4..7][2..3]; publish t+1
    if (tt + 2 < nt) stageB(tt + 2, 1);
    __builtin_amdgcn_s_barrier();
    asm volatile("" ::: "memory");
    __builtin_amdgcn_s_setprio(1);
#pragma unroll
    for (int ks = 0; ks < 2; ++ks)
#pragma unroll
      for (int i2 = 0; i2 < 4; ++i2)
#pragma unroll
        for (int j2 = 0; j2 < 2; ++j2)
          acc[4 + i2][2 + j2] = __builtin_amdgcn_mfma_f32_16x16x32_f16(
              a1[i2][ks], b1[j2][ks], acc[4 + i2][2 + j2], 0, 0, 0);
    __builtin_amdgcn_s_setprio(0);
    if (tt + 2 < nt) asm volatile("s_waitcnt vmcnt(4)" ::: "memory");
    else             asm volatile("s_waitcnt vmcnt(0)" ::: "memory");
    __builtin_amdgcn_s_barrier();
    asm volatile("" ::: "memory");
  }

  // epilogue: C elem (row,col): col = lane&15, row = (lane>>4)*4 + r
  const int colbase = n0 + wc * 64;
  if (MODE == 0 && colbase >= NI) return;
#pragma unroll
  for (int i = 0; i < 8; ++i) {
#pragma unroll
    for (int j = 0; j < 4; ++j) {
#pragma unroll
      for (int r = 0; r < 4; ++r) {
        int row = m0 + wr * 128 + i * 16 + kg * 4 + r;
        int col = colbase + j * 16 + lr;
        float x = acc[i][j][r];
        if (MODE == 0) {
          float xb = x + c0[col];
          float sv_ = xb * __builtin_amdgcn_rcpf(1.0f + __expf(-xb));   // silu
          if (colbase >= 3072) {             // qk stripes (colbase 3072 / 3136)
            int c = col - 3072;
            float pv = __shfl_xor(sv_, 1, 64);
            int pos = row & (SEQ - 1);
            float cv = c3[pos * HEAD + c], sn = c4[pos * HEAD + c];
            float q  = sv_ * c1[c] + c2[c];
            float pq = pv  * c1[c ^ 1] + c2[c ^ 1];
            float x2q = (c & 1) ? pq : -pq;
            outH2[row * HEAD + c] = (f16)(q * cv + x2q * sn);
            float kk = sv_ * c1[128 + c] + c2[128 + c];
            float pk = pv  * c1[128 + (c ^ 1)] + c2[128 + (c ^ 1)];
            float x2k = (c & 1) ? pk : -pk;
            outH3[row * HEAD + c] = (f16)(kk * cv + x2k * sn);
          } else {
            outH[(size_t)row * 3072 + col] = (f16)sv_;   // u | v
          }
        } else {   // MODE 2
          float uu = (float)hA[(size_t)row * 3072 + col];
          outH[(size_t)row * EDIM + col] = (f16)(x * uu);
        }
      }
    }
  }
}

// ---------------- scores: 128x128 2-phase dbuf (R3 structure), z = batch ----------------
__global__ __launch_bounds__(256, 4)
void gemm_scores(const f16* __restrict__ Q, const f16* __restrict__ Kt,
                 float* __restrict__ S, const float* __restrict__ am) {
  __shared__ f16 As0[128 * 32], As1[128 * 32], Bs0[128 * 32], Bs1[128 * 32];
  const int z = blockIdx.z;
  int bx, by;
  {
    int gx = gridDim.x;
    int id = blockIdx.y * gx + blockIdx.x;
    int cpx = (gx * gridDim.y) >> 3;
    int sw = (id & 7) * cpx + (id >> 3);
    bx = sw % gx; by = sw / gx;
  }
  const int m0 = by * 128, n0 = bx * 128;
  const int t = threadIdx.x;
  const int lane = t & 63, w = t >> 6;
  const int wr = w >> 1, wc = w & 1;
  const int lr = lane & 15, kg = lane >> 4;

  const f16* A = Q  + (size_t)z * SEQ * HEAD;
  const f16* B = Kt + (size_t)z * SEQ * HEAD;
  const f16* ga = A + (size_t)(m0 + (t >> 2)) * HEAD + (t & 3) * 8;
  const f16* gb = B + (size_t)(n0 + (t >> 2)) * HEAD + (t & 3) * 8;

  f32x4 acc[4][4];
#pragma unroll
  for (int i = 0; i < 4; ++i)
#pragma unroll
    for (int j = 0; j < 4; ++j) acc[i][j] = f32x4{0.f, 0.f, 0.f, 0.f};

  auto stage = [&](f16* AS, f16* BS, int kk) {
    gld_lds16(ga + kk,                     (char*)AS + w * 1024);
    gld_lds16(ga + (size_t)64 * HEAD + kk, (char*)AS + w * 1024 + 4096);
    gld_lds16(gb + kk,                     (char*)BS + w * 1024);
    gld_lds16(gb + (size_t)64 * HEAD + kk, (char*)BS + w * 1024 + 4096);
  };
  auto compute = [&](const f16* AS, const f16* BS) {
    f16x8 af[4], bf[4];
#pragma unroll
    for (int i = 0; i < 4; ++i) {
      af[i] = *(const f16x8*)&AS[(wr * 64 + i * 16 + lr) * 32 + kg * 8];
      bf[i] = *(const f16x8*)&BS[(wc * 64 + i * 16 + lr) * 32 + kg * 8];
    }
#pragma unroll
    for (int i = 0; i < 4; ++i)
#pragma unroll
      for (int j = 0; j < 4; ++j)
        acc[i][j] = __builtin_amdgcn_mfma_f32_16x16x32_f16(af[i], bf[j], acc[i][j], 0, 0, 0);
  };

  stage(As0, Bs0, 0);
  __syncthreads();
  for (int k0 = 0; k0 < HEAD; k0 += 64) {
    if (k0 + 32 < HEAD) stage(As1, Bs1, k0 + 32);
    compute(As0, Bs0);
    __syncthreads();
    if (k0 + 64 < HEAD) stage(As0, Bs0, k0 + 64);
    compute(As1, Bs1);
    __syncthreads();
  }

  float* outS = S + (size_t)z * SEQ * SEQ;
  const float* c = am + (size_t)z * SEQ;
#pragma unroll
  for (int i = 0; i < 4; ++i)
#pragma unroll
    for (int j = 0; j < 4; ++j)
#pragma unroll
      for (int r = 0; r < 4; ++r) {
        int row = m0 + wr * 64 + i * 16 + kg * 4 + r;
        int col = n0 + wc * 64 + j * 16 + lr;
        outS[(size_t)row * SEQ + col] = acc[i][j][r] * 0.08838834764831845f + c[col];
      }
}

// ---------------- final GEMM (N=768): 128x128 2-phase dbuf ----------------
__global__ __launch_bounds__(256, 4)
void gemm_final(const f16* __restrict__ A, int lda,
                const f16* __restrict__ Bt, int ldb, int K,
                float* __restrict__ outF, const float* __restrict__ c0) {
  __shared__ f16 As0[128 * 32], As1[128 * 32], Bs0[128 * 32], Bs1[128 * 32];
  int bx, by;
  {
    int gx = gridDim.x;
    int id = blockIdx.y * gx + blockIdx.x;
    int cpx = (gx * gridDim.y) >> 3;
    int sw = (id & 7) * cpx + (id >> 3);
    bx = sw % gx; by = sw / gx;
  }
  const int m0 = by * 128, n0 = bx * 128;
  const int t = threadIdx.x;
  const int lane = t & 63, w = t >> 6;
  const int wr = w >> 1, wc = w & 1;
  const int lr = lane & 15, kg = lane >> 4;

  const f16* ga = A  + (size_t)(m0 + (t >> 2)) * lda + (t & 3) * 8;
  const f16* gb = Bt + (size_t)(n0 + (t >> 2)) * ldb + (t & 3) * 8;

  f32x4 acc[4][4];
#pragma unroll
  for (int i = 0; i < 4; ++i)
#pragma unroll
    for (int j = 0; j < 4; ++j) acc[i][j] = f32x4{0.f, 0.f, 0.f, 0.f};

  auto stage = [&](f16* AS, f16* BS, int kk) {
    gld_lds16(ga + kk,                    (char*)AS + w * 1024);
    gld_lds16(ga + (size_t)64 * lda + kk, (char*)AS + w * 1024 + 4096);
    gld_lds16(gb + kk,                    (char*)BS + w * 1024);
    gld_lds16(gb + (size_t)64 * ldb + kk, (char*)BS + w * 1024 + 4096);
  };
  auto compute = [&](const f16* AS, const f16* BS) {
    f16x8 af[4], bf[4];
#pragma unroll
    for (int i = 0; i < 4; ++i) {
      af[i] = *(const f16x8*)&AS[(wr * 64 + i * 16 + lr) * 32 + kg * 8];
      bf[i] = *(const f16x8*)&BS[(wc * 64 + i * 16 + lr) * 32 + kg * 8];
    }
#pragma unroll
    for (int i = 0; i < 4; ++i)
#pragma unroll
      for (int j = 0; j < 4; ++j)
        acc[i][j] = __builtin_amdgcn_mfma_f32_16x16x32_f16(af[i], bf[j], acc[i][j], 0, 0, 0);
  };

  stage(As0, Bs0, 0);
  __syncthreads();
  for (int k0 = 0; k0 < K; k0 += 64) {
    if (k0 + 32 < K) stage(As1, Bs1, k0 + 32);
    compute(As0, Bs0);
    __syncthreads();
    if (k0 + 64 < K) stage(As0, Bs0, k0 + 64);
    compute(As1, Bs1);
    __syncthreads();
  }

#pragma unroll
  for (int i = 0; i < 4; ++i)
#pragma unroll
    for (int j = 0; j < 4; ++j)
#pragma unroll
      for (int r = 0; r < 4; ++r) {
        int row = m0 + wr * 64 + i * 16 + kg * 4 + r;
        int col = n0 + wc * 64 + j * 16 + lr;
        outF[(size_t)row * HDIM + col] = acc[i][j][r] + c0[col];
      }
}

// ---------------- softmax_plus: one block per row, in-place f32 -> f16 ----------------
__global__ __launch_bounds__(256) void softmax_plus_k(float* __restrict__ S) {
  __shared__ float red[4];
  const int t = threadIdx.x;
  float* sr = S + (size_t)blockIdx.x * SEQ;
  float v[8];
  *(float4*)&v[0] = ((const float4*)sr)[t * 2];
  *(float4*)&v[4] = ((const float4*)sr)[t * 2 + 1];

  float cnt = 0.f;
#pragma unroll
  for (int i = 0; i < 8; ++i) cnt += (v[i] > -1e11f) ? 1.0f : 0.0f;
#pragma unroll
  for (int o = 32; o; o >>= 1) cnt += __shfl_xor(cnt, o, 64);
  if ((t & 63) == 0) red[t >> 6] = cnt;
  __syncthreads();
  cnt = red[0] + red[1] + red[2] + red[3];
  float scale = __logf(fmaxf(cnt, 1.0f)) * 0.16025848f;   // 1/ln(512)

  float mx = -INFINITY;
#pragma unroll
  for (int i = 0; i < 8; ++i) { v[i] *= scale; mx = fmaxf(mx, v[i]); }
#pragma unroll
  for (int o = 32; o; o >>= 1) mx = fmaxf(mx, __shfl_xor(mx, o, 64));
  __syncthreads();
  if ((t & 63) == 0) red[t >> 6] = mx;
  __syncthreads();
  mx = fmaxf(fmaxf(red[0], red[1]), fmaxf(red[2], red[3]));

  float p[8], sum = 0.f;
#pragma unroll
  for (int i = 0; i < 8; ++i) { p[i] = __expf(v[i] - mx); sum += p[i]; }
#pragma unroll
  for (int o = 32; o; o >>= 1) sum += __shfl_xor(sum, o, 64);
  __syncthreads();
  if ((t & 63) == 0) red[t >> 6] = sum;
  __syncthreads();
  sum = red[0] + red[1] + red[2] + red[3];
  float inv = __builtin_amdgcn_rcpf(sum);

  union { f16 h[8]; uint4 u4; } pk;
#pragma unroll
  for (int i = 0; i < 8; ++i) pk.h[i] = (f16)(p[i] * inv);
  ((uint4*)sr)[t] = pk.u4;
}

// ---------------- launch ----------------
extern "C" void kernel_launch(void* const* d_in, const int* in_sizes, int n_in,
                              void* d_out, int out_size, void* d_ws, size_t ws_size,
                              hipStream_t stream) {
  const float* hs    = (const float*)d_in[0];
  const float* mask  = (const float*)d_in[1];
  const float* Wi    = (const float*)d_in[2];
  const float* bi    = (const float*)d_in[3];
  const float* gamma = (const float*)d_in[4];
  const float* beta  = (const float*)d_in[5];
  const float* Wo    = (const float*)d_in[6];
  const float* bo    = (const float*)d_in[7];
  float* out = (float*)d_out;

  const int nb = (ws_size >= ((size_t)200 << 20)) ? BATCH : 1;

  char* p = (char*)d_ws;
  auto alloc = [&](size_t b) { char* r = p; p += (b + 255) & ~(size_t)255; return r; };
  f16*   Xh   = (f16*)  alloc((size_t)MTOT * 3072 * 2);  // u|v
  f16*   Qh   = (f16*)  alloc((size_t)MTOT * HEAD * 2);
  f16*   Kh   = (f16*)  alloc((size_t)MTOT * HEAD * 2);
  f16*   Ah   = (f16*)  alloc((size_t)MTOT * HDIM * 2);
  f16*   WiT  = (f16*)  alloc((size_t)NIP * HDIM * 2);   // rows 3200..3327 pad (skipped cols)
  f16*   WoT  = (f16*)  alloc((size_t)HDIM * EDIM * 2);
  float* cosT = (float*)alloc((size_t)SEQ * HEAD * 4);
  float* sinT = (float*)alloc((size_t)SEQ * HEAD * 4);
  float* am   = (float*)alloc((size_t)BATCH * SEQ * 4);
  f16*   G    = (f16*)  alloc((size_t)MTOT * EDIM * 2);
  float* Sws  = (float*)alloc((size_t)nb * SEQ * SEQ * 4);
  f16*   Vt   = (f16*)  alloc((size_t)nb * EDIM * SEQ * 2);

  cast_f32_f16_k<<<dim3(MTOT * HDIM / 4 / 256), 256, 0, stream>>>(hs, Ah, MTOT * HDIM / 4);
  transpose_cast_k<<<dim3(NI / 32, HDIM / 32), 256, 0, stream>>>(Wi, NI, WiT, HDIM);
  transpose_cast_k<<<dim3(HDIM / 32, EDIM / 32), 256, 0, stream>>>(Wo, HDIM, WoT, EDIM);
  rope_tables_k<<<dim3(SEQ * 64 / 256), 256, 0, stream>>>(cosT, sinT);
  addmask_k<<<dim3(BATCH * SEQ / 256), 256, 0, stream>>>(mask, am);

  gemm8p<0><<<dim3(NIP / 256, MTOT / 256), 512, 0, stream>>>(
      Ah, HDIM, WiT, HDIM, 0, 30, HDIM,
      Xh, Qh, Kh, bi, gamma, beta, cosT, sinT, nullptr);

  const int bsh = (nb == BATCH) ? 3 : 30;
  for (int b0 = 0; b0 < BATCH; b0 += nb) {
    transpose_f16_k<<<dim3(EDIM / 32, SEQ / 32, nb), 256, 0, stream>>>(
        Xh + (size_t)b0 * SEQ * 3072 + 1536, 3072, (long long)SEQ * 3072,
        Vt, SEQ, (long long)EDIM * SEQ);
    gemm_scores<<<dim3(SEQ / 128, SEQ / 128, nb), 256, 0, stream>>>(
        Qh + (size_t)b0 * SEQ * HEAD, Kh + (size_t)b0 * SEQ * HEAD,
        Sws, am + b0 * SEQ);
    softmax_plus_k<<<dim3(nb * SEQ), 256, 0, stream>>>(Sws);
    gemm8p<2><<<dim3(EDIM / 256, nb * SEQ / 256), 512, 0, stream>>>(
        (const f16*)Sws, 4096, Vt, SEQ, (long long)EDIM * SEQ, bsh, SEQ,
        G + (size_t)b0 * SEQ * EDIM, nullptr, nullptr,
        nullptr, nullptr, nullptr, nullptr, nullptr,
        Xh + (size_t)b0 * SEQ * 3072);
  }

  gemm_final<<<dim3(HDIM / 128, MTOT / 128), 256, 0, stream>>>(
      G, EDIM, WoT, EDIM, EDIM, out, bo);
}

// Round 7
// 246.769 us; speedup vs baseline: 1.1626x; 1.1055x over previous
//
#include <hip/hip_runtime.h>
#include <math.h>

typedef _Float16 f16;
typedef _Float16 f16x8 __attribute__((ext_vector_type(8)));
typedef float f32x4 __attribute__((ext_vector_type(4)));

#define HEAD 128
#define EDIM 1536
#define NI   3200
#define HDIM 768
#define BATCH 4
#define SEQ  2048
#define MTOT (BATCH*SEQ)

__device__ __forceinline__ void gld_lds16(const void* g, void* l) {
  __builtin_amdgcn_global_load_lds(
      (const __attribute__((address_space(1))) void*)g,
      (__attribute__((address_space(3))) void*)l, 16, 0, 0);
}

// ---------------- prep kernels ----------------
__global__ __launch_bounds__(256) void cast_f32_f16_k(const float* __restrict__ in,
                                                      f16* __restrict__ out, int n4) {
  int i = blockIdx.x * 256 + threadIdx.x;
  if (i >= n4) return;
  float4 x = ((const float4*)in)[i];
  union { f16 h[4]; short4 s; } u;
  u.h[0] = (f16)x.x; u.h[1] = (f16)x.y; u.h[2] = (f16)x.z; u.h[3] = (f16)x.w;
  ((short4*)out)[i] = u.s;
}

__global__ __launch_bounds__(256) void transpose_cast_k(const float* __restrict__ in, int ld_in,
                                                        f16* __restrict__ out, int ld_out) {
  __shared__ float tile[32][33];
  int c = threadIdx.x & 31, r0 = threadIdx.x >> 5;
  int ib = blockIdx.y * 32, jb = blockIdx.x * 32;
#pragma unroll
  for (int rr = 0; rr < 32; rr += 8)
    tile[r0 + rr][c] = in[(size_t)(ib + r0 + rr) * ld_in + jb + c];
  __syncthreads();
#pragma unroll
  for (int rr = 0; rr < 32; rr += 8)
    out[(size_t)(jb + r0 + rr) * ld_out + ib + c] = (f16)tile[c][r0 + rr];
}

__global__ __launch_bounds__(256) void transpose_f16_k(const f16* __restrict__ in, int ld_in,
                                                       long long sIn,
                                                       f16* __restrict__ out, int ld_out,
                                                       long long sOut) {
  __shared__ f16 tile[32][33];
  in  += (size_t)blockIdx.z * sIn;
  out += (size_t)blockIdx.z * sOut;
  int c = threadIdx.x & 31, r0 = threadIdx.x >> 5;
  int ib = blockIdx.y * 32, jb = blockIdx.x * 32;
#pragma unroll
  for (int rr = 0; rr < 32; rr += 8)
    tile[r0 + rr][c] = in[(size_t)(ib + r0 + rr) * ld_in + jb + c];
  __syncthreads();
#pragma unroll
  for (int rr = 0; rr < 32; rr += 8)
    out[(size_t)(jb + r0 + rr) * ld_out + ib + c] = tile[c][r0 + rr];
}

__global__ __launch_bounds__(256) void rope_tables_k(float* __restrict__ cosT,
                                                     float* __restrict__ sinT) {
  int id = blockIdx.x * 256 + threadIdx.x;   // < 2048*64
  int pos = id >> 6, i = id & 63;
  float ang = (float)pos / powf(10000.0f, (float)(2 * i) / 128.0f);
  float cv = cosf(ang), sv = sinf(ang);
  cosT[pos * HEAD + 2 * i]     = cv;
  cosT[pos * HEAD + 2 * i + 1] = cv;
  sinT[pos * HEAD + 2 * i]     = sv;
  sinT[pos * HEAD + 2 * i + 1] = sv;
}

__global__ __launch_bounds__(256) void addmask_k(const float* __restrict__ mask,
                                                 float* __restrict__ am) {
  int i = blockIdx.x * 256 + threadIdx.x;    // BATCH*SEQ
  am[i] = (1.0f - mask[i]) * -1e12f;
}

// ---------- 128x128 2-phase dbuf GEMM (R3 structure, proven best at short K) ----------
// MODE 0: GEMM1 -> silu, u/v to Xh; qk cols -> gamma/beta + RoPE -> Qh,Kh
// MODE 3: final -> + bo, f32 out
template <int MODE>
__global__ __launch_bounds__(256, 4)
void gemm_bt(const f16* __restrict__ A, int lda,
             const f16* __restrict__ Bt, int ldb, int K,
             float* __restrict__ outF,
             f16* __restrict__ outH, f16* __restrict__ outH2, f16* __restrict__ outH3,
             const float* __restrict__ c0, const float* __restrict__ c1,
             const float* __restrict__ c2, const float* __restrict__ c3,
             const float* __restrict__ c4) {
  __shared__ f16 As0[128 * 32], As1[128 * 32], Bs0[128 * 32], Bs1[128 * 32];
  const int m0 = blockIdx.y * 128, n0 = blockIdx.x * 128;
  const int t = threadIdx.x;
  const int lane = t & 63, w = t >> 6;
  const int wr = w >> 1, wc = w & 1;
  const int lr = lane & 15, kg = lane >> 4;

  const f16* ga = A  + (size_t)(m0 + (t >> 2)) * lda + (t & 3) * 8;
  const f16* gb = Bt + (size_t)(n0 + (t >> 2)) * ldb + (t & 3) * 8;

  f32x4 acc[4][4];
#pragma unroll
  for (int i = 0; i < 4; ++i)
#pragma unroll
    for (int j = 0; j < 4; ++j) acc[i][j] = f32x4{0.f, 0.f, 0.f, 0.f};

  auto stage = [&](f16* AS, f16* BS, int kk) {
    gld_lds16(ga + kk,                    (char*)AS + w * 1024);
    gld_lds16(ga + (size_t)64 * lda + kk, (char*)AS + w * 1024 + 4096);
    gld_lds16(gb + kk,                    (char*)BS + w * 1024);
    gld_lds16(gb + (size_t)64 * ldb + kk, (char*)BS + w * 1024 + 4096);
  };
  auto compute = [&](const f16* AS, const f16* BS) {
    f16x8 af[4], bf[4];
#pragma unroll
    for (int i = 0; i < 4; ++i) {
      af[i] = *(const f16x8*)&AS[(wr * 64 + i * 16 + lr) * 32 + kg * 8];
      bf[i] = *(const f16x8*)&BS[(wc * 64 + i * 16 + lr) * 32 + kg * 8];
    }
#pragma unroll
    for (int i = 0; i < 4; ++i)
#pragma unroll
      for (int j = 0; j < 4; ++j)
        acc[i][j] = __builtin_amdgcn_mfma_f32_16x16x32_f16(af[i], bf[j], acc[i][j], 0, 0, 0);
  };

  stage(As0, Bs0, 0);
  __syncthreads();
  for (int k0 = 0; k0 < K; k0 += 64) {
    if (k0 + 32 < K) stage(As1, Bs1, k0 + 32);
    compute(As0, Bs0);
    __syncthreads();
    if (k0 + 64 < K) stage(As0, Bs0, k0 + 64);
    compute(As1, Bs1);
    __syncthreads();
  }

  // epilogue: C elem (row, col): col = lane&15, row = (lane>>4)*4 + r   [measured layout]
#pragma unroll
  for (int i = 0; i < 4; ++i) {
#pragma unroll
    for (int j = 0; j < 4; ++j) {
#pragma unroll
      for (int r = 0; r < 4; ++r) {
        int row = m0 + wr * 64 + i * 16 + kg * 4 + r;
        int col = n0 + wc * 64 + j * 16 + lr;
        float x = acc[i][j][r];
        if (MODE == 0) {
          float xb = x + c0[col];
          float s = xb * __builtin_amdgcn_rcpf(1.0f + __expf(-xb));   // silu
          if (blockIdx.x == 24) {                   // qk tile (cols 3072..3199)
            int c = col - 3072;
            float pv = __shfl_xor(s, 1, 64);        // partner column c^1 lives in lane^1
            int pos = row & (SEQ - 1);
            float cv = c3[pos * HEAD + c], sv = c4[pos * HEAD + c];
            float q  = s  * c1[c]       + c2[c];
            float pq = pv * c1[c ^ 1]   + c2[c ^ 1];
            float x2q = (c & 1) ? pq : -pq;
            outH2[row * HEAD + c] = (f16)(q * cv + x2q * sv);
            float kk = s  * c1[128 + c]       + c2[128 + c];
            float pk = pv * c1[128 + (c ^ 1)] + c2[128 + (c ^ 1)];
            float x2k = (c & 1) ? pk : -pk;
            outH3[row * HEAD + c] = (f16)(kk * cv + x2k * sv);
          } else {
            outH[(size_t)row * 3072 + col] = (f16)s;   // u | v
          }
        } else {
          outF[(size_t)row * HDIM + col] = x + c0[col];
        }
      }
    }
  }
}

// ---------- scores: 128x128 2-phase, K=128, f16 out to DENSE P [z][2048][2048] ----------
__global__ __launch_bounds__(256, 4)
void gemm_scores(const f16* __restrict__ Q, const f16* __restrict__ Kt,
                 f16* __restrict__ P, const float* __restrict__ am) {
  __shared__ f16 As0[128 * 32], As1[128 * 32], Bs0[128 * 32], Bs1[128 * 32];
  const int z = blockIdx.z;
  const int m0 = blockIdx.y * 128, n0 = blockIdx.x * 128;
  const int t = threadIdx.x;
  const int lane = t & 63, w = t >> 6;
  const int wr = w >> 1, wc = w & 1;
  const int lr = lane & 15, kg = lane >> 4;

  const f16* A = Q  + (size_t)z * SEQ * HEAD;
  const f16* B = Kt + (size_t)z * SEQ * HEAD;
  const f16* ga = A + (size_t)(m0 + (t >> 2)) * HEAD + (t & 3) * 8;
  const f16* gb = B + (size_t)(n0 + (t >> 2)) * HEAD + (t & 3) * 8;

  f32x4 acc[4][4];
#pragma unroll
  for (int i = 0; i < 4; ++i)
#pragma unroll
    for (int j = 0; j < 4; ++j) acc[i][j] = f32x4{0.f, 0.f, 0.f, 0.f};

  auto stage = [&](f16* AS, f16* BS, int kk) {
    gld_lds16(ga + kk,                     (char*)AS + w * 1024);
    gld_lds16(ga + (size_t)64 * HEAD + kk, (char*)AS + w * 1024 + 4096);
    gld_lds16(gb + kk,                     (char*)BS + w * 1024);
    gld_lds16(gb + (size_t)64 * HEAD + kk, (char*)BS + w * 1024 + 4096);
  };
  auto compute = [&](const f16* AS, const f16* BS) {
    f16x8 af[4], bf[4];
#pragma unroll
    for (int i = 0; i < 4; ++i) {
      af[i] = *(const f16x8*)&AS[(wr * 64 + i * 16 + lr) * 32 + kg * 8];
      bf[i] = *(const f16x8*)&BS[(wc * 64 + i * 16 + lr) * 32 + kg * 8];
    }
#pragma unroll
    for (int i = 0; i < 4; ++i)
#pragma unroll
      for (int j = 0; j < 4; ++j)
        acc[i][j] = __builtin_amdgcn_mfma_f32_16x16x32_f16(af[i], bf[j], acc[i][j], 0, 0, 0);
  };

  stage(As0, Bs0, 0);
  __syncthreads();
  for (int k0 = 0; k0 < HEAD; k0 += 64) {
    if (k0 + 32 < HEAD) stage(As1, Bs1, k0 + 32);
    compute(As0, Bs0);
    __syncthreads();
    if (k0 + 64 < HEAD) stage(As0, Bs0, k0 + 64);
    compute(As1, Bs1);
    __syncthreads();
  }

  f16* outP = P + (size_t)z * SEQ * SEQ;
  const float* c = am + (size_t)z * SEQ;
#pragma unroll
  for (int i = 0; i < 4; ++i)
#pragma unroll
    for (int j = 0; j < 4; ++j)
#pragma unroll
      for (int r = 0; r < 4; ++r) {
        int row = m0 + wr * 64 + i * 16 + kg * 4 + r;
        int col = n0 + wc * 64 + j * 16 + lr;
        // -1e12 mask add overflows to f16 -inf; softmax clamps on read
        outP[(size_t)row * SEQ + col] = (f16)(acc[i][j][r] * 0.08838834764831845f + c[col]);
      }
}

// ============ 256x256 8-wave 8-phase GEMM for PV (K=2048: template sweet spot) ============
// MODE 2 only: attn @ v -> * u gate, f16 out. Batches flattened in grid.y (bshift).
template <int MODE>
__global__ __launch_bounds__(512, 2)
void gemm8p(const f16* __restrict__ A, int lda,
            const f16* __restrict__ B0, int ldb, long long sB, int bshift, int K,
            f16* __restrict__ outH, const f16* __restrict__ hA) {
  __shared__ f16 LS[2][2][2][2][4096];  // [buf][mat][half][p] = 128 KiB
  int bx, by;
  {
    int gx = gridDim.x;
    int id = blockIdx.y * gx + blockIdx.x;
    int cpx = (gx * gridDim.y) >> 3;
    int sw = (id & 7) * cpx + (id >> 3);
    bx = sw % gx; by = sw / gx;
  }
  const int m0 = by * 256, n0 = bx * 256;
  const int t = threadIdx.x;
  const int lane = t & 63, w = t >> 6;
  const int wr = w >> 2, wc = w & 3;      // 2M x 4N waves; per-wave C = 128x64
  const int lr = lane & 15, kg = lane >> 4;
  const int bb = by >> bshift;
  const f16* Bb = B0 + (size_t)bb * sB;

  const int rb = t >> 3;
  const int sl = ((t & 7) ^ (rb & 7)) << 3;          // swizzled 16B slot (T2, both sides)
  const f16* gA = A  + (size_t)(m0 + rb) * lda + sl;
  const f16* gB = Bb + (size_t)(n0 + rb) * ldb + sl;
  char* lA = (char*)LS + w * 1024;
  char* lB = (char*)LS + 32768 + w * 1024;

  auto stageA = [&](int kt, int h) {
    const f16* s = gA + (size_t)(h << 7) * lda + (kt << 6);
    char* d = lA + ((kt & 1) << 16) + (h << 14);
    gld_lds16(s, d);
    gld_lds16(s + ((size_t)lda << 6), d + 8192);
  };
  auto stageB = [&](int kt, int h) {
    const f16* s = gB + (size_t)(h << 7) * ldb + (kt << 6);
    char* d = lB + ((kt & 1) << 16) + (h << 14);
    gld_lds16(s, d);
    gld_lds16(s + ((size_t)ldb << 6), d + 8192);
  };

  const char* RA = (const char*)LS + ((wr * 128 + lr) << 7);
  const char* RB = (const char*)LS + 32768 + ((wc * 64 + lr) << 7);
  const int sw0 = (kg ^ (lr & 7)) << 4;
  const int sw1 = ((4 + kg) ^ (lr & 7)) << 4;

  f32x4 acc[8][4];
#pragma unroll
  for (int i = 0; i < 8; ++i)
#pragma unroll
    for (int j = 0; j < 4; ++j) acc[i][j] = f32x4{0.f, 0.f, 0.f, 0.f};

  const int nt = K >> 6;
  stageA(0, 0); stageA(0, 1); stageB(0, 0); stageB(0, 1);
  asm volatile("" ::: "memory");
  if (nt > 1) {
    stageB(1, 0); stageB(1, 1);
    asm volatile("s_waitcnt vmcnt(4)" ::: "memory");
  } else {
    asm volatile("s_waitcnt vmcnt(0)" ::: "memory");
  }
  __builtin_amdgcn_s_barrier();
  asm volatile("" ::: "memory");

  for (int tt = 0; tt < nt; ++tt) {
    const char* SA = RA + ((tt & 1) << 16);
    const char* SB = RB + ((tt & 1) << 16);
    f16x8 a0[4][2], a1[4][2], b0[2][2], b1[2][2];
    // phase 0: read a0,b0; stage A0(t+1); MFMA acc[0..3][0..1]
#pragma unroll
    for (int i2 = 0; i2 < 4; ++i2) {
      a0[i2][0] = *(const f16x8*)(SA + (i2 << 11) + sw0);
      a0[i2][1] = *(const f16x8*)(SA + (i2 << 11) + sw1);
    }
#pragma unroll
    for (int j2 = 0; j2 < 2; ++j2) {
      b0[j2][0] = *(const f16x8*)(SB + (j2 << 11) + sw0);
      b0[j2][1] = *(const f16x8*)(SB + (j2 << 11) + sw1);
    }
    if (tt + 1 < nt) stageA(tt + 1, 0);
    __builtin_amdgcn_s_barrier();
    asm volatile("" ::: "memory");
    __builtin_amdgcn_s_setprio(1);
#pragma unroll
    for (int ks = 0; ks < 2; ++ks)
#pragma unroll
      for (int i2 = 0; i2 < 4; ++i2)
#pragma unroll
        for (int j2 = 0; j2 < 2; ++j2)
          acc[i2][j2] = __builtin_amdgcn_mfma_f32_16x16x32_f16(
              a0[i2][ks], b0[j2][ks], acc[i2][j2], 0, 0, 0);
    __builtin_amdgcn_s_setprio(0);
    __builtin_amdgcn_s_barrier();
    asm volatile("" ::: "memory");
    // phase 1: read b1; stage A1(t+1); MFMA acc[0..3][2..3]
#pragma unroll
    for (int j2 = 0; j2 < 2; ++j2) {
      b1[j2][0] = *(const f16x8*)(SB + ((2 + j2) << 11) + sw0);
      b1[j2][1] = *(const f16x8*)(SB + ((2 + j2) << 11) + sw1);
    }
    if (tt + 1 < nt) stageA(tt + 1, 1);
    __builtin_amdgcn_s_barrier();
    asm volatile("" ::: "memory");
    __builtin_amdgcn_s_setprio(1);
#pragma unroll
    for (int ks = 0; ks < 2; ++ks)
#pragma unroll
      for (int i2 = 0; i2 < 4; ++i2)
#pragma unroll
        for (int j2 = 0; j2 < 2; ++j2)
          acc[i2][2 + j2] = __builtin_amdgcn_mfma_f32_16x16x32_f16(
              a0[i2][ks], b1[j2][ks], acc[i2][2 + j2], 0, 0, 0);
    __builtin_amdgcn_s_setprio(0);
    __builtin_amdgcn_s_barrier();
    asm volatile("" ::: "memory");
    // phase 2: read a1; stage B0(t+2); MFMA acc[4..7][0..1]
#pragma unroll
    for (int i2 = 0; i2 < 4; ++i2) {
      a1[i2][0] = *(const f16x8*)(SA + ((4 + i2) << 11) + sw0);
      a1[i2][1] = *(const f16x8*)(SA + ((4 + i2) << 11) + sw1);
    }
    if (tt + 2 < nt) stageB(tt + 2, 0);
    __builtin_amdgcn_s_barrier();
    asm volatile("" ::: "memory");
    __builtin_amdgcn_s_setprio(1);
#pragma unroll
    for (int ks = 0; ks < 2; ++ks)
#pragma unroll
      for (int i2 = 0; i2 < 4; ++i2)
#pragma unroll
        for (int j2 = 0; j2 < 2; ++j2)
          acc[4 + i2][j2] = __builtin_amdgcn_mfma_f32_16x16x32_f16(
              a1[i2][ks], b0[j2][ks], acc[4 + i2][j2], 0, 0, 0);
    __builtin_amdgcn_s_setprio(0);
    __builtin_amdgcn_s_barrier();
    asm volatile("" ::: "memory");
    // phase 3: stage B1(t+2); MFMA acc[4..7][2..3]; retire tile t+1
    if (tt + 2 < nt) stageB(tt + 2, 1);
    __builtin_amdgcn_s_barrier();
    asm volatile("" ::: "memory");
    __builtin_amdgcn_s_setprio(1);
#pragma unroll
    for (int ks = 0; ks < 2; ++ks)
#pragma unroll
      for (int i2 = 0; i2 < 4; ++i2)
#pragma unroll
        for (int j2 = 0; j2 < 2; ++j2)
          acc[4 + i2][2 + j2] = __builtin_amdgcn_mfma_f32_16x16x32_f16(
              a1[i2][ks], b1[j2][ks], acc[4 + i2][2 + j2], 0, 0, 0);
    __builtin_amdgcn_s_setprio(0);
    if (tt + 2 < nt) asm volatile("s_waitcnt vmcnt(4)" ::: "memory");
    else             asm volatile("s_waitcnt vmcnt(0)" ::: "memory");
    __builtin_amdgcn_s_barrier();
    asm volatile("" ::: "memory");
  }

  const int colbase = n0 + wc * 64;
#pragma unroll
  for (int i = 0; i < 8; ++i) {
#pragma unroll
    for (int j = 0; j < 4; ++j) {
#pragma unroll
      for (int r = 0; r < 4; ++r) {
        int row = m0 + wr * 128 + i * 16 + kg * 4 + r;
        int col = colbase + j * 16 + lr;
        float uu = (float)hA[(size_t)row * 3072 + col];   // u gate
        outH[(size_t)row * EDIM + col] = (f16)(acc[i][j][r] * uu);
      }
    }
  }
}

// ---------- softmax_plus on dense f16 P, in place: one block per row ----------
__global__ __launch_bounds__(256) void softmax_plus_f16(f16* __restrict__ P) {
  __shared__ float red[4];
  const int t = threadIdx.x;
  f16* pr = P + (size_t)blockIdx.x * SEQ;
  union { uint4 u4; f16 h[8]; } ld;
  ld.u4 = ((const uint4*)pr)[t];
  float v[8];
#pragma unroll
  for (int i = 0; i < 8; ++i) v[i] = fmaxf((float)ld.h[i], -1e12f);  // -inf -> -1e12

  float cnt = 0.f;
#pragma unroll
  for (int i = 0; i < 8; ++i) cnt += (v[i] > -1e11f) ? 1.0f : 0.0f;
#pragma unroll
  for (int o = 32; o; o >>= 1) cnt += __shfl_xor(cnt, o, 64);
  if ((t & 63) == 0) red[t >> 6] = cnt;
  __syncthreads();
  cnt = red[0] + red[1] + red[2] + red[3];
  float scale = __logf(fmaxf(cnt, 1.0f)) * 0.16025848f;   // 1/ln(512)

  float mx = -INFINITY;
#pragma unroll
  for (int i = 0; i < 8; ++i) { v[i] *= scale; mx = fmaxf(mx, v[i]); }
#pragma unroll
  for (int o = 32; o; o >>= 1) mx = fmaxf(mx, __shfl_xor(mx, o, 64));
  __syncthreads();
  if ((t & 63) == 0) red[t >> 6] = mx;
  __syncthreads();
  mx = fmaxf(fmaxf(red[0], red[1]), fmaxf(red[2], red[3]));

  float p[8], sum = 0.f;
#pragma unroll
  for (int i = 0; i < 8; ++i) { p[i] = __expf(v[i] - mx); sum += p[i]; }
#pragma unroll
  for (int o = 32; o; o >>= 1) sum += __shfl_xor(sum, o, 64);
  __syncthreads();
  if ((t & 63) == 0) red[t >> 6] = sum;
  __syncthreads();
  sum = red[0] + red[1] + red[2] + red[3];
  float inv = __builtin_amdgcn_rcpf(sum);

  union { f16 h[8]; uint4 u4; } pk;
#pragma unroll
  for (int i = 0; i < 8; ++i) pk.h[i] = (f16)(p[i] * inv);
  ((uint4*)pr)[t] = pk.u4;   // own 16B, no cross-thread hazard
}

// ---------------- launch ----------------
extern "C" void kernel_launch(void* const* d_in, const int* in_sizes, int n_in,
                              void* d_out, int out_size, void* d_ws, size_t ws_size,
                              hipStream_t stream) {
  const float* hs    = (const float*)d_in[0];
  const float* mask  = (const float*)d_in[1];
  const float* Wi    = (const float*)d_in[2];
  const float* bi    = (const float*)d_in[3];
  const float* gamma = (const float*)d_in[4];
  const float* beta  = (const float*)d_in[5];
  const float* Wo    = (const float*)d_in[6];
  const float* bo    = (const float*)d_in[7];
  float* out = (float*)d_out;

  const int nb = (ws_size >= ((size_t)170 << 20)) ? BATCH : 1;

  char* p = (char*)d_ws;
  auto alloc = [&](size_t b) { char* r = p; p += (b + 255) & ~(size_t)255; return r; };
  f16*   Xh   = (f16*)  alloc((size_t)MTOT * 3072 * 2);  // u|v
  f16*   Qh   = (f16*)  alloc((size_t)MTOT * HEAD * 2);
  f16*   Kh   = (f16*)  alloc((size_t)MTOT * HEAD * 2);
  f16*   Ah   = (f16*)  alloc((size_t)MTOT * HDIM * 2);
  f16*   WiT  = (f16*)  alloc((size_t)NI * HDIM * 2);
  f16*   WoT  = (f16*)  alloc((size_t)HDIM * EDIM * 2);
  float* cosT = (float*)alloc((size_t)SEQ * HEAD * 4);
  float* sinT = (float*)alloc((size_t)SEQ * HEAD * 4);
  float* am   = (float*)alloc((size_t)BATCH * SEQ * 4);
  f16*   G    = (f16*)  alloc((size_t)MTOT * EDIM * 2);
  f16*   P    = (f16*)  alloc((size_t)nb * SEQ * SEQ * 2);   // dense f16 scores/attn
  f16*   Vt   = (f16*)  alloc((size_t)nb * EDIM * SEQ * 2);

  cast_f32_f16_k<<<dim3(MTOT * HDIM / 4 / 256), 256, 0, stream>>>(hs, Ah, MTOT * HDIM / 4);
  transpose_cast_k<<<dim3(NI / 32, HDIM / 32), 256, 0, stream>>>(Wi, NI, WiT, HDIM);
  transpose_cast_k<<<dim3(HDIM / 32, EDIM / 32), 256, 0, stream>>>(Wo, HDIM, WoT, EDIM);
  rope_tables_k<<<dim3(SEQ * 64 / 256), 256, 0, stream>>>(cosT, sinT);
  addmask_k<<<dim3(BATCH * SEQ / 256), 256, 0, stream>>>(mask, am);

  gemm_bt<0><<<dim3(NI / 128, MTOT / 128), 256, 0, stream>>>(
      Ah, HDIM, WiT, HDIM, HDIM,
      nullptr, Xh, Qh, Kh, bi, gamma, beta, cosT, sinT);

  const int bsh = (nb == BATCH) ? 3 : 30;
  for (int b0 = 0; b0 < BATCH; b0 += nb) {
    transpose_f16_k<<<dim3(EDIM / 32, SEQ / 32, nb), 256, 0, stream>>>(
        Xh + (size_t)b0 * SEQ * 3072 + 1536, 3072, (long long)SEQ * 3072,
        Vt, SEQ, (long long)EDIM * SEQ);
    gemm_scores<<<dim3(SEQ / 128, SEQ / 128, nb), 256, 0, stream>>>(
        Qh + (size_t)b0 * SEQ * HEAD, Kh + (size_t)b0 * SEQ * HEAD,
        P, am + b0 * SEQ);
    softmax_plus_f16<<<dim3(nb * SEQ), 256, 0, stream>>>(P);
    gemm8p<2><<<dim3(EDIM / 256, nb * SEQ / 256), 512, 0, stream>>>(
        P, SEQ, Vt, SEQ, (long long)EDIM * SEQ, bsh, SEQ,
        G + (size_t)b0 * SEQ * EDIM,
        Xh + (size_t)b0 * SEQ * 3072);
  }

  gemm_bt<3><<<dim3(HDIM / 128, MTOT / 128), 256, 0, stream>>>(
      G, EDIM, WoT, EDIM, EDIM,
      out, nullptr, nullptr, nullptr, bo, nullptr, nullptr, nullptr, nullptr);
}